// Round 8
// baseline (11216.843 us; speedup 1.0000x reference)
//
#include <hip/hip_runtime.h>
#include <math.h>

// Problem constants
#define SEQ 2048
#define EMB_D 512
#define HID 512
#define NTAGS 12
#define START_TAG 10
#define STOP_TAG 11
#define NEGV (-10000.0f)
#define POISON 0xAAAAAAAAu

__device__ __forceinline__ float sigf(float x) { return 1.0f / (1.0f + expf(-x)); }

// sc0 (L1-bypass, XCD-L2-coherent) 8B load + drain. Only the poll load is in
// flight when this runs (Gi prefetch is depth-2, long completed).
__device__ __forceinline__ unsigned long long ld_sc0_u64(const float* p) {
    unsigned long long ap = (unsigned long long)p;
    unsigned long long v;
    asm volatile("global_load_dwordx2 %0, %1, off sc0\n\ts_waitcnt vmcnt(0)"
                 : "=v"(v)
                 : "v"(ap));
    return v;
}
// sc0 4B store: lands in the local XCD L2 (fast same-XCD visibility).
__device__ __forceinline__ void st_sc0_f32(float* p, float x) {
    unsigned long long ap = (unsigned long long)p;
    asm volatile("global_store_dword %0, %1, off sc0" ::"v"(ap), "v"(x));
}
__device__ __forceinline__ bool pois2(unsigned long long x) {
    return (unsigned)x == POISON || (unsigned)(x >> 32) == POISON;
}

// ---------------------------------------------------------------------------
// K0: embedding gather  x0[t][e] = emb[sentence[t]][e]
// ---------------------------------------------------------------------------
__global__ void k_embed(const int* __restrict__ sent, const float* __restrict__ emb,
                        float* __restrict__ x0) {
    int t = blockIdx.x;
    int tid = threadIdx.x;  // 128 threads, 128 float4 = 512 floats
    int row = sent[t];
    const float4* src = (const float4*)(emb + (size_t)row * EMB_D);
    float4* dst = (float4*)(x0 + (size_t)t * EMB_D);
    dst[tid] = src[tid];
}

// ---------------------------------------------------------------------------
// K1/K3: fp32 GEMM — 128x128 tile, BK=16, 256 threads, 8x8/thread.
// Accumulation strictly k-ascending per output -> bit-identical to ref.
// ---------------------------------------------------------------------------
#define GBM 128
#define GBN 128
#define GBK 16
#define GLD 132

__global__ __launch_bounds__(256) void k_gemm(
    const float* __restrict__ Af, const float* __restrict__ Ab,
    const float* __restrict__ B,
    const float* __restrict__ biasA, const float* __restrict__ biasB,
    float* __restrict__ C, int K) {
    const int N = 2048;
    int dir = blockIdx.z;
    const float* Bd = B + (size_t)dir * N * K;
    const float* bA = biasA + dir * N;
    const float* bB = biasB + dir * N;
    float* Cd = C + (size_t)dir * 2048 * N;
    int m0 = blockIdx.y * GBM, n0 = blockIdx.x * GBN;

    __shared__ float As[GBK * GLD];
    __shared__ float Bs[GBK * GLD];

    int tid = threadIdx.x;
    int lrow = tid >> 1;        // 0..127
    int lk = (tid & 1) * 8;     // 0 or 8
    int tx = tid & 15, ty = tid >> 4;

    float acc[8][8] = {};

    for (int kt = 0; kt < K; kt += GBK) {
        {
            int m = m0 + lrow;
            const float* base = (kt < 512) ? (Af + (size_t)m * 512 + kt)
                                           : (Ab + (size_t)m * 512 + (kt - 512));
            float4 v0 = *(const float4*)(base + lk);
            float4 v1 = *(const float4*)(base + lk + 4);
            As[(lk + 0) * GLD + lrow] = v0.x;
            As[(lk + 1) * GLD + lrow] = v0.y;
            As[(lk + 2) * GLD + lrow] = v0.z;
            As[(lk + 3) * GLD + lrow] = v0.w;
            As[(lk + 4) * GLD + lrow] = v1.x;
            As[(lk + 5) * GLD + lrow] = v1.y;
            As[(lk + 6) * GLD + lrow] = v1.z;
            As[(lk + 7) * GLD + lrow] = v1.w;
        }
        {
            int n = n0 + lrow;
            const float* base = Bd + (size_t)n * K + kt;
            float4 v0 = *(const float4*)(base + lk);
            float4 v1 = *(const float4*)(base + lk + 4);
            Bs[(lk + 0) * GLD + lrow] = v0.x;
            Bs[(lk + 1) * GLD + lrow] = v0.y;
            Bs[(lk + 2) * GLD + lrow] = v0.z;
            Bs[(lk + 3) * GLD + lrow] = v0.w;
            Bs[(lk + 4) * GLD + lrow] = v1.x;
            Bs[(lk + 5) * GLD + lrow] = v1.y;
            Bs[(lk + 6) * GLD + lrow] = v1.z;
            Bs[(lk + 7) * GLD + lrow] = v1.w;
        }
        __syncthreads();
#pragma unroll
        for (int kk = 0; kk < GBK; ++kk) {
            float4 a0 = *(const float4*)&As[kk * GLD + ty * 8];
            float4 a1 = *(const float4*)&As[kk * GLD + ty * 8 + 4];
            float4 b0 = *(const float4*)&Bs[kk * GLD + tx * 8];
            float4 b1 = *(const float4*)&Bs[kk * GLD + tx * 8 + 4];
            float av[8] = {a0.x, a0.y, a0.z, a0.w, a1.x, a1.y, a1.z, a1.w};
            float bv[8] = {b0.x, b0.y, b0.z, b0.w, b1.x, b1.y, b1.z, b1.w};
#pragma unroll
            for (int i = 0; i < 8; ++i)
#pragma unroll
                for (int j = 0; j < 8; ++j) acc[i][j] += av[i] * bv[j];
        }
        __syncthreads();
    }
#pragma unroll
    for (int i = 0; i < 8; ++i) {
        int m = m0 + ty * 8 + i;
#pragma unroll
        for (int j = 0; j < 8; ++j) {
            int n = n0 + tx * 8 + j;
            Cd[(size_t)m * N + n] = acc[i][j] + bA[n] + bB[n];
        }
    }
}

// ---------------------------------------------------------------------------
// K2/K4: LSTM recurrence (R4 body; R8 = XCD-local communication).
//  - Grid 256, participate iff (bid&7)<2: under the round-robin WG->XCD
//    dispatch each direction's 32 WGs land on ONE XCD and share its L2
//    (R5 measured FETCH 107->36MB: mapping + sc0 L2-service confirmed).
//  - Producers dual-store h: sc0 store (local-L2 visibility, ~200cy) AND the
//    proven agent-scope atomic store (MALL anchor). Write-once, same value.
//  - Consumers: sc0-only spin (LIMIT tries). On exhaustion: sticky
//    fast_ok=false -> R4's agent loop (with sc0 interleave). Correctness
//    never depends on the XCD mapping; worst case is one slow step then
//    exactly R4 behavior. (R5's mistake: only 6 fast tries, then detection
//    landed on the slow alternating path every step.)
//  - Depth-2 Gi prefetch: the poll's vmcnt drain must never wait on a
//    streaming HBM miss now that detection is ~L2-fast.
//  - FP arithmetic identical to R4 -> bit-identical outputs.
// ---------------------------------------------------------------------------
#define HPAD 132   // padded section stride (floats); 132 mod 32 = 4 banks
#define SC0_LIMIT 64

__global__ __launch_bounds__(256, 1) void k_lstm(
    const float* __restrict__ Whh,  // [2][2048][512]
    const float* __restrict__ Gi,   // [2][2048][2048]  (Wih@x + bih + bhh)
    float* __restrict__ hstore)     // [2][2048][512], pre-poisoned 0xAA
{
    int bid = blockIdx.x;
    int xsel = bid & 7;
    if (xsel >= 2) return;          // only two XCD groups participate
    int dir = xsel;
    int slice = bid >> 3;           // 0..31
    int u_base = slice * 16;
    int tid = threadIdx.x;

    const float* Whh_d = Whh + (size_t)dir * 2048 * 512;
    const float* Gi_d = Gi + (size_t)dir * 2048 * 2048;
    float* h_d = hstore + (size_t)dir * 2048 * 512;

    int rl = tid >> 2;   // local gate row 0..63
    int kp = tid & 3;    // k-quarter
    int gg = rl >> 4;    // gate (i,f,g,o)
    int uu = rl & 15;    // unit offset 0..15
    int r = gg * 512 + u_base + uu;  // global gate-row in [0,2048)

    // weights: w[j] = Whh[dir][r][kp*128 + j]
    float w[128];
    {
        const float* wsrc = Whh_d + (size_t)r * 512 + kp * 128;
#pragma unroll
        for (int j = 0; j < 128; j += 4) {
            float4 v = *(const float4*)(wsrc + j);
            w[j] = v.x; w[j + 1] = v.y; w[j + 2] = v.z; w[j + 3] = v.w;
        }
    }

    __shared__ __align__(16) float hlds[4 * HPAD];  // 4 padded k-sections
    __shared__ float gdot[64];
    float c_reg = 0.0f;
    bool fast_ok = true;   // sticky: sc0 fast path usable for my line

    int sec = tid >> 6;
    int soff = (tid & 63) * 2;
    float* hstage = hlds + sec * HPAD + soff;

    // depth-2 Gi prefetch pipeline (kp==0 lanes only)
    float gi = 0.f, gi1 = 0.f;
    if (kp == 0) {
        int t0 = dir ? 2047 : 0;
        int t1 = dir ? 2046 : 1;
        gi = Gi_d[(size_t)t0 * 2048 + r];
        gi1 = Gi_d[(size_t)t1 * 2048 + r];
    }

    for (int it = 0; it < 2048; ++it) {
        int t = dir ? (2047 - it) : it;

        if (it == 0) {
            hstage[0] = 0.f;
            hstage[1] = 0.f;
        } else {
            int tprev = dir ? (t + 1) : (t - 1);
            const float* srcf = h_d + (size_t)tprev * 512 + 2 * tid;
            unsigned long long v = 0xAAAAAAAAAAAAAAAAull;
            if (fast_ok) {
                int tries = 0;
                for (;;) {
                    v = ld_sc0_u64(srcf);
                    if (!pois2(v)) break;
                    if (++tries >= SC0_LIMIT) { fast_ok = false; break; }
                }
            }
            if (pois2(v)) {
                // agent anchor loop (R4-proven) with sc0 interleave
                const unsigned long long* src = (const unsigned long long*)srcf;
                for (;;) {
                    v = __hip_atomic_load(src, __ATOMIC_RELAXED,
                                          __HIP_MEMORY_SCOPE_AGENT);
                    if (!pois2(v)) break;
                    v = ld_sc0_u64(srcf);
                    if (!pois2(v)) break;
                }
            }
            hstage[0] = __uint_as_float((unsigned)v);
            hstage[1] = __uint_as_float((unsigned)(v >> 32));
        }
        __syncthreads();

        // issue Gi load for step it+2 (completes ~2 steps before use)
        float gi2 = 0.f;
        if (kp == 0 && it + 2 < 2048) {
            int tn2 = dir ? (t - 2) : (t + 2);
            gi2 = Gi_d[(size_t)tn2 * 2048 + r];
        }

        // partial dot over this thread's k-quarter (conflict-free padded reads)
        float p = 0.f;
        const float4* h4 = (const float4*)(hlds + kp * HPAD);
#pragma unroll
        for (int j4 = 0; j4 < 32; ++j4) {
            float4 hv = h4[j4];
            p += w[4 * j4 + 0] * hv.x;
            p += w[4 * j4 + 1] * hv.y;
            p += w[4 * j4 + 2] * hv.z;
            p += w[4 * j4 + 3] * hv.w;
        }
        p += __shfl_xor(p, 1);
        p += __shfl_xor(p, 2);
        if (kp == 0) {
            float v = p + gi;
            gdot[rl] = (gg == 2) ? tanhf(v) : sigf(v);
        }
        __syncthreads();

        if (tid < 16) {
            float iv = gdot[0 * 16 + tid];  // sig(i)
            float fv = gdot[1 * 16 + tid];  // sig(f)
            float gv = gdot[2 * 16 + tid];  // tanh(g)
            float ov = gdot[3 * 16 + tid];  // sig(o)
            float c = fv * c_reg + iv * gv;
            float h = ov * tanhf(c);
            c_reg = c;
            float* dst = h_d + (size_t)t * 512 + u_base + tid;
            st_sc0_f32(dst, h);   // fast local-L2 visibility
            __hip_atomic_store(dst, h, __ATOMIC_RELAXED,
                               __HIP_MEMORY_SCOPE_AGENT);  // MALL anchor
        }
        gi = gi1;
        gi1 = gi2;
        // no trailing barrier: next iteration's hlds/gdot writes are
        // separated from this iteration's reads by the two barriers above.
    }
}

// ---------------------------------------------------------------------------
// K5: feats[t][tag] = concat(h1f[t],h1b[t]) . W_tag[tag] + b_tag[tag]
// ---------------------------------------------------------------------------
__global__ __launch_bounds__(64) void k_feats(
    const float* __restrict__ h1, const float* __restrict__ Wt,
    const float* __restrict__ bt, float* __restrict__ feats) {
    int t = blockIdx.x;
    int lane = threadIdx.x;
    __shared__ __align__(16) float xl[1024];
    const float4* hf = (const float4*)(h1 + (size_t)t * 512);
    const float4* hb = (const float4*)(h1 + (size_t)(2048 + t) * 512);
    ((float4*)xl)[lane] = hf[lane];
    ((float4*)xl)[lane + 64] = hf[lane + 64];
    ((float4*)xl)[128 + lane] = hb[lane];
    ((float4*)xl)[128 + lane + 64] = hb[lane + 64];
    __syncthreads();
    for (int tag = 0; tag < NTAGS; ++tag) {
        const float* wrow = Wt + tag * 1024;
        float s = 0.f;
        for (int k = lane; k < 1024; k += 64) s += xl[k] * wrow[k];
#pragma unroll
        for (int off = 32; off; off >>= 1) s += __shfl_xor(s, off);
        if (lane == 0) feats[t * NTAGS + tag] = s + bt[tag];
    }
}

// ---------------------------------------------------------------------------
// K6: Viterbi forward + backtrack, single 64-thread block.
// ---------------------------------------------------------------------------
__global__ __launch_bounds__(64) void k_viterbi(
    const float* __restrict__ feats, const float* __restrict__ trans,
    float* __restrict__ out) {
    __shared__ float fv[2][NTAGS];
    __shared__ unsigned char bp[SEQ * NTAGS];  // 24 KB
    __shared__ float featbuf[256 * NTAGS];     // 12 KB
    __shared__ float term[NTAGS];
    int lane = threadIdx.x;

    float tr[NTAGS];
    if (lane < NTAGS) {
#pragma unroll
        for (int p = 0; p < NTAGS; ++p) tr[p] = trans[lane * NTAGS + p];
        fv[0][lane] = (lane == START_TAG) ? 0.f : NEGV;
    }
    __syncthreads();

    int cur = 0;
    for (int tc = 0; tc < SEQ; tc += 256) {
        for (int i = lane; i < 256 * NTAGS; i += 64) featbuf[i] = feats[tc * NTAGS + i];
        __syncthreads();
        for (int tt = 0; tt < 256; ++tt) {
            int t = tc + tt;
            if (lane < NTAGS) {
                float best = fv[cur][0] + tr[0];
                int bi = 0;
#pragma unroll
                for (int p = 1; p < NTAGS; ++p) {
                    float s = fv[cur][p] + tr[p];
                    if (s > best) { best = s; bi = p; }  // strict > keeps first max
                }
                bp[t * NTAGS + lane] = (unsigned char)bi;
                fv[cur ^ 1][lane] = best + featbuf[tt * NTAGS + lane];
            }
            cur ^= 1;
            __syncthreads();
        }
    }

    if (lane < NTAGS) term[lane] = fv[cur][lane] + trans[STOP_TAG * NTAGS + lane];
    __syncthreads();
    if (lane == 0) {
        float best = term[0];
        int bi = 0;
        for (int p = 1; p < NTAGS; ++p) {
            if (term[p] > best) { best = term[p]; bi = p; }
        }
        out[0] = best;
        int tag = bi;
        out[1 + (SEQ - 1)] = (float)tag;
        for (int t = SEQ - 1; t >= 1; --t) {
            tag = bp[t * NTAGS + tag];
            out[t] = (float)tag;
        }
    }
}

// ---------------------------------------------------------------------------
extern "C" void kernel_launch(void* const* d_in, const int* in_sizes, int n_in,
                              void* d_out, int out_size, void* d_ws, size_t ws_size,
                              hipStream_t stream) {
    const int* sent = (const int*)d_in[0];
    const float* emb = (const float*)d_in[1];
    const float* Wih0 = (const float*)d_in[2];
    const float* Whh0 = (const float*)d_in[3];
    const float* bih0 = (const float*)d_in[4];
    const float* bhh0 = (const float*)d_in[5];
    const float* Wih1 = (const float*)d_in[6];
    const float* Whh1 = (const float*)d_in[7];
    const float* bih1 = (const float*)d_in[8];
    const float* bhh1 = (const float*)d_in[9];
    const float* Wtag = (const float*)d_in[10];
    const float* btag = (const float*)d_in[11];
    const float* trans = (const float*)d_in[12];
    float* out = (float*)d_out;

    char* ws = (char*)d_ws;
    size_t off = 0;
    auto alloc = [&](size_t bytes) {
        void* p = ws + off;
        off += (bytes + 255) & ~(size_t)255;
        return p;
    };
    float* x0 = (float*)alloc(2048ull * 512 * 4);          // 4 MB
    float* Gi = (float*)alloc(2ull * 2048 * 2048 * 4);     // 32 MB (reused layer0/1)
    float* h0 = (float*)alloc(2ull * 2048 * 512 * 4);      // 8 MB
    float* h1 = (float*)alloc(2ull * 2048 * 512 * 4);      // 8 MB
    float* feats = (float*)alloc(2048ull * NTAGS * 4);

    // poison h buffers: "not yet written" sentinel for the data-polling sync
    hipMemsetAsync(h0, 0xAA, 2ull * 2048 * 512 * 4, stream);
    hipMemsetAsync(h1, 0xAA, 2ull * 2048 * 512 * 4, stream);

    k_embed<<<2048, 128, 0, stream>>>(sent, emb, x0);

    dim3 gg(16, 16, 2);
    // layer 0 input gates: Gi = x0 @ Wih0^T + bih0 + bhh0  (K=512)
    k_gemm<<<gg, 256, 0, stream>>>(x0, x0, Wih0, bih0, bhh0, Gi, 512);
    // layer 0 recurrence (256 WGs; 64 participate, XCD-selected by bid&7)
    k_lstm<<<256, 256, 0, stream>>>(Whh0, Gi, h0);
    // layer 1 input gates: Gi = concat(h0f,h0b) @ Wih1^T + b  (K=1024)
    k_gemm<<<gg, 256, 0, stream>>>(h0, h0 + 2048ull * 512, Wih1, bih1, bhh1, Gi, 1024);
    // layer 1 recurrence
    k_lstm<<<256, 256, 0, stream>>>(Whh1, Gi, h1);
    // tag projection
    k_feats<<<2048, 64, 0, stream>>>(h1, Wtag, btag, feats);
    // viterbi decode
    k_viterbi<<<1, 64, 0, stream>>>(feats, trans, out);
}